// Round 2
// baseline (564.142 us; speedup 1.0000x reference)
//
#include <hip/hip_runtime.h>

typedef unsigned short u16;
typedef unsigned int u32;
typedef __bf16 bf16x8 __attribute__((ext_vector_type(8)));
typedef float f32x4 __attribute__((ext_vector_type(4)));

#define B_ 2
#define S_ 2048
#define D_ 2048
#define H_ 16
#define HD_ 128

__device__ __forceinline__ u16 f2bf(float f) {
  u32 u = __float_as_uint(f);
  u32 r = (u + 0x7fffu + ((u >> 16) & 1u)) >> 16;
  return (u16)r;
}
__device__ __forceinline__ float bf2f(u16 b) {
  return __uint_as_float(((u32)b) << 16);
}

// async global->LDS, 16B per lane. LDS dest must be linear in lane order.
__device__ __forceinline__ void gll16(const void* g, void* lds) {
  __builtin_amdgcn_global_load_lds(
      (const __attribute__((address_space(1))) u32*)g,
      (__attribute__((address_space(3))) u32*)lds, 16, 0, 0);
}

// ---------------- f32 -> bf16 cast ----------------
__global__ __launch_bounds__(256) void cvt_bf16(const float* __restrict__ in,
                                                u16* __restrict__ out, int n4) {
  int i = blockIdx.x * 256 + threadIdx.x;
  if (i >= n4) return;
  float4 v = ((const float4*)in)[i];
  u16 o[4] __attribute__((aligned(8)));
  o[0] = f2bf(v.x); o[1] = f2bf(v.y); o[2] = f2bf(v.z); o[3] = f2bf(v.w);
  ((ushort4*)out)[i] = *(const ushort4*)o;
}

// ---------------- RoPE (in-place on (B,H,S,HD) bf16), optional scale ----------------
__global__ __launch_bounds__(256) void rope_k(u16* __restrict__ x,
                                              const float* __restrict__ cosb,
                                              const float* __restrict__ sinb,
                                              float scale) {
  int tid = blockIdx.x * 256 + threadIdx.x;  // 8 elems per thread
  int flat = tid << 3;
  int hd0 = flat & (HD_ - 1);
  int s = (flat >> 7) & (S_ - 1);
  u16 e[8] __attribute__((aligned(16)));
  *(uint4*)e = *(const uint4*)&x[flat];
  const float* cp = cosb + s * (HD_ / 2) + (hd0 >> 1);
  const float* sp = sinb + s * (HD_ / 2) + (hd0 >> 1);
#pragma unroll
  for (int i = 0; i < 4; ++i) {
    float xr = bf2f(e[2 * i]), xi = bf2f(e[2 * i + 1]);
    float c = cp[i], sn = sp[i];
    e[2 * i]     = f2bf((xr * c - xi * sn) * scale);
    e[2 * i + 1] = f2bf((xr * sn + xi * c) * scale);
  }
  *(uint4*)&x[flat] = *(const uint4*)e;
}

// ---------------- V transpose: (B,H,S,HD) -> (B,H,HD,S) ----------------
__global__ __launch_bounds__(256) void transpose_v(const u16* __restrict__ v,
                                                   u16* __restrict__ vt) {
  __shared__ u16 tile[64][72];
  int s0 = blockIdx.x * 64, hd0 = blockIdx.y * 64, bh = blockIdx.z;
  const u16* vh = v + (size_t)bh * S_ * HD_;
  u16* vth = vt + (size_t)bh * S_ * HD_;
  int t = threadIdx.x;
#pragma unroll
  for (int it = 0; it < 2; ++it) {
    int f = it * 256 + t;
    int r = f >> 3, c = (f & 7) * 8;
    *(uint4*)&tile[r][c] = *(const uint4*)&vh[(size_t)(s0 + r) * HD_ + hd0 + c];
  }
  __syncthreads();
#pragma unroll
  for (int it = 0; it < 2; ++it) {
    int f = it * 256 + t;
    int r = f >> 3, c = (f & 7) * 8;   // r: hd row of vt, c: s col chunk
    u16 tmp[8] __attribute__((aligned(16)));
#pragma unroll
    for (int j = 0; j < 8; ++j) tmp[j] = tile[c + j][r];
    *(uint4*)&vth[(size_t)(hd0 + r) * S_ + s0 + c] = *(const uint4*)tmp;
  }
}

// ---------------- GEMM C[m,n] = sum_k A[m,k]*W[n,k]  (M=4096,N=2048,K=2048) ----------------
// m97 structure: 128x128 tile, BK=64, 4 waves (2x2), global_load_lds width=16.
// outf32==0: writes bf16 to Db permuted (B,H,S,HD). outf32==1: writes f32 to DF (B,S,D).
__global__ __launch_bounds__(256) void gemm_bt(
    const u16* __restrict__ A,
    const u16* __restrict__ Wq, const u16* __restrict__ Wk, const u16* __restrict__ Wv,
    u16* __restrict__ Dq, u16* __restrict__ Dk, u16* __restrict__ Dv,
    float* __restrict__ DF, int outf32) {
  const u16* W = (blockIdx.z == 0) ? Wq : (blockIdx.z == 1) ? Wk : Wv;
  u16* Db = (blockIdx.z == 0) ? Dq : (blockIdx.z == 1) ? Dk : Dv;
  __shared__ u16 At[128 * 64] __attribute__((aligned(16)));
  __shared__ u16 Bt[128 * 64] __attribute__((aligned(16)));
  const int t = threadIdx.x, l = t & 63;
  const int w = t >> 6, wr = w >> 1, wc = w & 1;
  const int m0 = blockIdx.y * 128, n0 = blockIdx.x * 128;
  f32x4 acc[4][4];
#pragma unroll
  for (int i = 0; i < 4; ++i)
#pragma unroll
    for (int j = 0; j < 4; ++j) acc[i][j] = (f32x4){0.f, 0.f, 0.f, 0.f};
  const int row_s = t >> 3;
  const int col_s = (t & 7) * 8;
  for (int kt = 0; kt < 2048; kt += 64) {
    __syncthreads();
#pragma unroll
    for (int it = 0; it < 4; ++it) {
      int f = it * 256 + t;
      int row = it * 32 + row_s;
      gll16(&A[(size_t)(m0 + row) * 2048 + kt + col_s], &At[f * 8]);
      gll16(&W[(size_t)(n0 + row) * 2048 + kt + col_s], &Bt[f * 8]);
    }
    __syncthreads();
#pragma unroll
    for (int kk = 0; kk < 2; ++kk) {
      const int ko = kk * 32 + (l >> 4) * 8;
      bf16x8 av[4], bv[4];
#pragma unroll
      for (int i = 0; i < 4; ++i)
        av[i] = *(const bf16x8*)&At[(wr * 64 + i * 16 + (l & 15)) * 64 + ko];
#pragma unroll
      for (int i = 0; i < 4; ++i)
        bv[i] = *(const bf16x8*)&Bt[(wc * 64 + i * 16 + (l & 15)) * 64 + ko];
#pragma unroll
      for (int i = 0; i < 4; ++i)
#pragma unroll
        for (int j = 0; j < 4; ++j)
          acc[i][j] = __builtin_amdgcn_mfma_f32_16x16x32_bf16(av[i], bv[j], acc[i][j], 0, 0, 0);
    }
  }
#pragma unroll
  for (int i = 0; i < 4; ++i) {
#pragma unroll
    for (int j = 0; j < 4; ++j) {
#pragma unroll
      for (int r = 0; r < 4; ++r) {
        int m = m0 + wr * 64 + i * 16 + (l >> 4) * 4 + r;
        int n = n0 + wc * 64 + j * 16 + (l & 15);
        float val = acc[i][j][r];
        if (outf32) {
          DF[(size_t)m * 2048 + n] = val;
        } else {
          int b = m >> 11, s = m & 2047, h = n >> 7, hd = n & 127;
          Db[(((size_t)(b * 16 + h)) * 2048 + s) * 128 + hd] = f2bf(val);
        }
      }
    }
  }
}

// ---------------- Flash attention: q,k (B,H,S,HD), vt (B,H,HD,S), o (B,S,D) bf16 ----------------
// q pre-scaled by (1/sqrt(HD))*log2(e) so softmax uses exp2.
// Pairing for causal balance: block x handles q-tiles {x, 31-x} -> uniform 33 kv-tiles/block.
// T14 staging: prologue-load tile regs; per tile: barrier, ds_write, issue next loads, barrier, compute.
__global__ __launch_bounds__(256) void attn_fwd(
    const u16* __restrict__ q, const u16* __restrict__ k, const u16* __restrict__ vt,
    u16* __restrict__ o) {
  const int bh = blockIdx.y;
  const u16* qh = q + (size_t)bh * S_ * HD_;
  const u16* kh = k + (size_t)bh * S_ * HD_;
  const u16* vth = vt + (size_t)bh * S_ * HD_;
  const int t = threadIdx.x, l = t & 63, w = t >> 6;
  __shared__ u16 Kl[64][136] __attribute__((aligned(16)));   // +8 pad: 2-way banks
  __shared__ u16 Vl[128][72] __attribute__((aligned(16)));   // [hd][kv], +8 pad
  __shared__ u16 Pl[4][16][72] __attribute__((aligned(16))); // per-wave P
  const int b = bh >> 4, h = bh & 15;
  // staging geometry (constant across tiles): thread t covers
  // K rows it*16 + (t>>4), cols (t&15)*8 ; V rows it*32 + (t>>3), cols (t&7)*8
  const int krr = t >> 4, krc = (t & 15) * 8;
  const int vrr = t >> 3, vrc = (t & 7) * 8;

  for (int half = 0; half < 2; ++half) {
    const int qt = half ? (31 - (int)blockIdx.x) : (int)blockIdx.x;
    const int q0 = qt * 64;
    const int qrow = q0 + w * 16 + (l & 15);
    bf16x8 qf[4];
#pragma unroll
    for (int kk = 0; kk < 4; ++kk)
      qf[kk] = *(const bf16x8*)&qh[(size_t)qrow * HD_ + kk * 32 + (l >> 4) * 8];
    f32x4 oacc[8];
#pragma unroll
    for (int i = 0; i < 8; ++i) oacc[i] = (f32x4){0.f, 0.f, 0.f, 0.f};
    float mrow[4] = {-1e30f, -1e30f, -1e30f, -1e30f};
    float lrow[4] = {0.f, 0.f, 0.f, 0.f};

    uint4 rk[4], rv[4];
#pragma unroll
    for (int it = 0; it < 4; ++it) {   // prologue: tile 0 into regs
      rk[it] = *(const uint4*)&kh[(size_t)(it * 16 + krr) * HD_ + krc];
      rv[it] = *(const uint4*)&vth[(size_t)(it * 32 + vrr) * S_ + vrc];
    }

    for (int tk = 0; tk <= qt; ++tk) {
      __syncthreads();                 // previous compute done: LDS writable
#pragma unroll
      for (int it = 0; it < 4; ++it)
        *(uint4*)&Kl[it * 16 + krr][krc] = rk[it];
#pragma unroll
      for (int it = 0; it < 4; ++it)
        *(uint4*)&Vl[it * 32 + vrr][vrc] = rv[it];
      if (tk < qt) {                   // issue next tile's loads; latency hides under compute
        const int kv1 = (tk + 1) * 64;
#pragma unroll
        for (int it = 0; it < 4; ++it) {
          rk[it] = *(const uint4*)&kh[(size_t)(kv1 + it * 16 + krr) * HD_ + krc];
          rv[it] = *(const uint4*)&vth[(size_t)(it * 32 + vrr) * S_ + kv1 + vrc];
        }
      }
      __syncthreads();                 // LDS tile ready

      f32x4 sf[4];
#pragma unroll
      for (int cb = 0; cb < 4; ++cb) sf[cb] = (f32x4){0.f, 0.f, 0.f, 0.f};
#pragma unroll
      for (int kk = 0; kk < 4; ++kk) {
        const int ko = kk * 32 + (l >> 4) * 8;
#pragma unroll
        for (int cb = 0; cb < 4; ++cb) {
          bf16x8 bfr = *(const bf16x8*)&Kl[cb * 16 + (l & 15)][ko];
          sf[cb] = __builtin_amdgcn_mfma_f32_16x16x32_bf16(qf[kk], bfr, sf[cb], 0, 0, 0);
        }
      }
      if (tk == qt) {  // causal mask on diagonal tile
        const int rbase = w * 16 + (l >> 4) * 4;
#pragma unroll
        for (int cb = 0; cb < 4; ++cb) {
          int c = cb * 16 + (l & 15);
#pragma unroll
          for (int r = 0; r < 4; ++r)
            if (c > rbase + r) sf[cb][r] = -1e30f;
        }
      }
      float fr[4], ps[4];
#pragma unroll
      for (int r = 0; r < 4; ++r) {
        float v0 = fmaxf(fmaxf(sf[0][r], sf[1][r]), fmaxf(sf[2][r], sf[3][r]));
        v0 = fmaxf(v0, __shfl_xor(v0, 1));
        v0 = fmaxf(v0, __shfl_xor(v0, 2));
        v0 = fmaxf(v0, __shfl_xor(v0, 4));
        v0 = fmaxf(v0, __shfl_xor(v0, 8));
        float Mn = fmaxf(mrow[r], v0);
        fr[r] = exp2f(mrow[r] - Mn);
        mrow[r] = Mn;
        ps[r] = 0.f;
      }
#pragma unroll
      for (int cb = 0; cb < 4; ++cb) {
#pragma unroll
        for (int r = 0; r < 4; ++r) {
          float p = exp2f(sf[cb][r] - mrow[r]);
          ps[r] += p;
          Pl[w][(l >> 4) * 4 + r][cb * 16 + (l & 15)] = f2bf(p);
        }
      }
#pragma unroll
      for (int r = 0; r < 4; ++r) {
        float s = ps[r];
        s += __shfl_xor(s, 1);
        s += __shfl_xor(s, 2);
        s += __shfl_xor(s, 4);
        s += __shfl_xor(s, 8);
        lrow[r] = lrow[r] * fr[r] + s;
      }
#pragma unroll
      for (int i = 0; i < 8; ++i)
#pragma unroll
        for (int r = 0; r < 4; ++r) oacc[i][r] *= fr[r];
#pragma unroll
      for (int ks = 0; ks < 2; ++ks) {
        bf16x8 pa = *(const bf16x8*)&Pl[w][l & 15][ks * 32 + (l >> 4) * 8];
#pragma unroll
        for (int nf = 0; nf < 8; ++nf) {
          bf16x8 vb = *(const bf16x8*)&Vl[nf * 16 + (l & 15)][ks * 32 + (l >> 4) * 8];
          oacc[nf] = __builtin_amdgcn_mfma_f32_16x16x32_bf16(pa, vb, oacc[nf], 0, 0, 0);
        }
      }
    }

    float inv[4];
#pragma unroll
    for (int r = 0; r < 4; ++r) inv[r] = 1.f / lrow[r];
#pragma unroll
    for (int nf = 0; nf < 8; ++nf) {
#pragma unroll
      for (int r = 0; r < 4; ++r) {
        int row = q0 + w * 16 + (l >> 4) * 4 + r;
        int col = h * 128 + nf * 16 + (l & 15);
        o[((size_t)(b * 2048 + row)) * 2048 + col] = f2bf(oacc[nf][r] * inv[r]);
      }
    }
  }
}

extern "C" void kernel_launch(void* const* d_in, const int* in_sizes, int n_in,
                              void* d_out, int out_size, void* d_ws, size_t ws_size,
                              hipStream_t stream) {
  (void)in_sizes; (void)n_in; (void)out_size; (void)ws_size;
  const float* hs   = (const float*)d_in[0];
  const float* fcos = (const float*)d_in[1];
  const float* fsin = (const float*)d_in[2];
  // d_in[3] = attention_mask: causal, implemented directly.
  const float* wq = (const float*)d_in[4];
  const float* wk = (const float*)d_in[5];
  const float* wv = (const float*)d_in[6];
  const float* wo = (const float*)d_in[7];
  float* out = (float*)d_out;
  char* ws = (char*)d_ws;
  // ws layout (bytes), total 128 MiB
  u16* hsb = (u16*)(ws + 0);          // 16 MiB  hs bf16 (B,S,D)
  u16* wqb = (u16*)(ws + 16777216);
  u16* wkb = (u16*)(ws + 25165824);
  u16* wvb = (u16*)(ws + 33554432);
  u16* wob = (u16*)(ws + 41943040);
  u16* qb  = (u16*)(ws + 50331648);   // (B,H,S,HD) bf16
  u16* kb  = (u16*)(ws + 67108864);
  u16* vb  = (u16*)(ws + 83886080);
  u16* vtb = (u16*)(ws + 100663296);  // (B,H,HD,S) bf16
  u16* aob = (u16*)(ws + 117440512);  // (B,S,D) bf16 attention output

  cvt_bf16<<<8192, 256, 0, stream>>>(hs, hsb, 2097152);
  cvt_bf16<<<4096, 256, 0, stream>>>(wq, wqb, 1048576);
  cvt_bf16<<<4096, 256, 0, stream>>>(wk, wkb, 1048576);
  cvt_bf16<<<4096, 256, 0, stream>>>(wv, wvb, 1048576);
  cvt_bf16<<<4096, 256, 0, stream>>>(wo, wob, 1048576);

  gemm_bt<<<dim3(16, 32, 3), 256, 0, stream>>>(hsb, wqb, wkb, wvb, qb, kb, vb, nullptr, 0);

  const float qscale = (float)(0.08838834764831845 * 1.4426950408889634); // 1/sqrt(128)*log2(e)
  rope_k<<<4096, 256, 0, stream>>>(qb, fcos, fsin, qscale);
  rope_k<<<4096, 256, 0, stream>>>(kb, fcos, fsin, 1.0f);

  transpose_v<<<dim3(32, 2, 32), 256, 0, stream>>>(vb, vtb);

  attn_fwd<<<dim3(16, 32), 256, 0, stream>>>(qb, kb, vtb, aob);

  gemm_bt<<<dim3(16, 32, 1), 256, 0, stream>>>(aob, wob, wob, wob,
                                               nullptr, nullptr, nullptr, out, 1);
}

// Round 5
// 467.037 us; speedup vs baseline: 1.2079x; 1.2079x over previous
//
#include <hip/hip_runtime.h>

typedef unsigned short u16;
typedef unsigned int u32;
typedef __bf16 bf16x8 __attribute__((ext_vector_type(8)));
typedef float f32x4 __attribute__((ext_vector_type(4)));

#define B_ 2
#define S_ 2048
#define D_ 2048
#define H_ 16
#define HD_ 128

__device__ __forceinline__ u16 f2bf(float f) {
  u32 u = __float_as_uint(f);
  u32 r = (u + 0x7fffu + ((u >> 16) & 1u)) >> 16;
  return (u16)r;
}
__device__ __forceinline__ float bf2f(u16 b) {
  return __uint_as_float(((u32)b) << 16);
}

// async global->LDS, 16B per lane. LDS dest must be linear in lane order.
__device__ __forceinline__ void gll16(const void* g, void* lds) {
  __builtin_amdgcn_global_load_lds(
      (const __attribute__((address_space(1))) u32*)g,
      (__attribute__((address_space(3))) u32*)lds, 16, 0, 0);
}

// ---------------- f32 -> bf16 cast ----------------
__global__ __launch_bounds__(256) void cvt_bf16(const float* __restrict__ in,
                                                u16* __restrict__ out, int n4) {
  int i = blockIdx.x * 256 + threadIdx.x;
  if (i >= n4) return;
  float4 v = ((const float4*)in)[i];
  u16 o[4] __attribute__((aligned(8)));
  o[0] = f2bf(v.x); o[1] = f2bf(v.y); o[2] = f2bf(v.z); o[3] = f2bf(v.w);
  ((ushort4*)out)[i] = *(const ushort4*)o;
}

// ---------------- RoPE (in-place on (B,H,S,HD) bf16), optional scale ----------------
__global__ __launch_bounds__(256) void rope_k(u16* __restrict__ x,
                                              const float* __restrict__ cosb,
                                              const float* __restrict__ sinb,
                                              float scale) {
  int tid = blockIdx.x * 256 + threadIdx.x;  // 8 elems per thread
  int flat = tid << 3;
  int hd0 = flat & (HD_ - 1);
  int s = (flat >> 7) & (S_ - 1);
  u16 e[8] __attribute__((aligned(16)));
  *(uint4*)e = *(const uint4*)&x[flat];
  const float* cp = cosb + s * (HD_ / 2) + (hd0 >> 1);
  const float* sp = sinb + s * (HD_ / 2) + (hd0 >> 1);
#pragma unroll
  for (int i = 0; i < 4; ++i) {
    float xr = bf2f(e[2 * i]), xi = bf2f(e[2 * i + 1]);
    float c = cp[i], sn = sp[i];
    e[2 * i]     = f2bf((xr * c - xi * sn) * scale);
    e[2 * i + 1] = f2bf((xr * sn + xi * c) * scale);
  }
  *(uint4*)&x[flat] = *(const uint4*)e;
}

// ---------------- V transpose: (B,H,S,HD) -> (B,H,HD,S) ----------------
__global__ __launch_bounds__(256) void transpose_v(const u16* __restrict__ v,
                                                   u16* __restrict__ vt) {
  __shared__ u16 tile[64][72];
  int s0 = blockIdx.x * 64, hd0 = blockIdx.y * 64, bh = blockIdx.z;
  const u16* vh = v + (size_t)bh * S_ * HD_;
  u16* vth = vt + (size_t)bh * S_ * HD_;
  int t = threadIdx.x;
#pragma unroll
  for (int it = 0; it < 2; ++it) {
    int f = it * 256 + t;
    int r = f >> 3, c = (f & 7) * 8;
    *(uint4*)&tile[r][c] = *(const uint4*)&vh[(size_t)(s0 + r) * HD_ + hd0 + c];
  }
  __syncthreads();
#pragma unroll
  for (int it = 0; it < 2; ++it) {
    int f = it * 256 + t;
    int r = f >> 3, c = (f & 7) * 8;   // r: hd row of vt, c: s col chunk
    u16 tmp[8] __attribute__((aligned(16)));
#pragma unroll
    for (int j = 0; j < 8; ++j) tmp[j] = tile[c + j][r];
    *(uint4*)&vth[(size_t)(hd0 + r) * S_ + s0 + c] = *(const uint4*)tmp;
  }
}

// ---------------- GEMM C[m,n] = sum_k A[m,k]*W[n,k]  (M=4096,N=2048,K=2048) ----------------
// m97 structure: 128x128 tile, BK=64, 4 waves (2x2), global_load_lds width=16.
// outf32==0: writes bf16 to Db permuted (B,H,S,HD). outf32==1: writes f32 to DF (B,S,D).
__global__ __launch_bounds__(256) void gemm_bt(
    const u16* __restrict__ A,
    const u16* __restrict__ Wq, const u16* __restrict__ Wk, const u16* __restrict__ Wv,
    u16* __restrict__ Dq, u16* __restrict__ Dk, u16* __restrict__ Dv,
    float* __restrict__ DF, int outf32) {
  const u16* W = (blockIdx.z == 0) ? Wq : (blockIdx.z == 1) ? Wk : Wv;
  u16* Db = (blockIdx.z == 0) ? Dq : (blockIdx.z == 1) ? Dk : Dv;
  __shared__ u16 At[128 * 64] __attribute__((aligned(16)));
  __shared__ u16 Bt[128 * 64] __attribute__((aligned(16)));
  const int t = threadIdx.x, l = t & 63;
  const int w = t >> 6, wr = w >> 1, wc = w & 1;
  const int m0 = blockIdx.y * 128, n0 = blockIdx.x * 128;
  f32x4 acc[4][4];
#pragma unroll
  for (int i = 0; i < 4; ++i)
#pragma unroll
    for (int j = 0; j < 4; ++j) acc[i][j] = (f32x4){0.f, 0.f, 0.f, 0.f};
  const int row_s = t >> 3;
  const int col_s = (t & 7) * 8;
  for (int kt = 0; kt < 2048; kt += 64) {
    __syncthreads();
#pragma unroll
    for (int it = 0; it < 4; ++it) {
      int f = it * 256 + t;
      int row = it * 32 + row_s;
      gll16(&A[(size_t)(m0 + row) * 2048 + kt + col_s], &At[f * 8]);
      gll16(&W[(size_t)(n0 + row) * 2048 + kt + col_s], &Bt[f * 8]);
    }
    __syncthreads();
#pragma unroll
    for (int kk = 0; kk < 2; ++kk) {
      const int ko = kk * 32 + (l >> 4) * 8;
      bf16x8 av[4], bv[4];
#pragma unroll
      for (int i = 0; i < 4; ++i)
        av[i] = *(const bf16x8*)&At[(wr * 64 + i * 16 + (l & 15)) * 64 + ko];
#pragma unroll
      for (int i = 0; i < 4; ++i)
        bv[i] = *(const bf16x8*)&Bt[(wc * 64 + i * 16 + (l & 15)) * 64 + ko];
#pragma unroll
      for (int i = 0; i < 4; ++i)
#pragma unroll
        for (int j = 0; j < 4; ++j)
          acc[i][j] = __builtin_amdgcn_mfma_f32_16x16x32_bf16(av[i], bv[j], acc[i][j], 0, 0, 0);
    }
  }
#pragma unroll
  for (int i = 0; i < 4; ++i) {
#pragma unroll
    for (int j = 0; j < 4; ++j) {
#pragma unroll
      for (int r = 0; r < 4; ++r) {
        int m = m0 + wr * 64 + i * 16 + (l >> 4) * 4 + r;
        int n = n0 + wc * 64 + j * 16 + (l & 15);
        float val = acc[i][j][r];
        if (outf32) {
          DF[(size_t)m * 2048 + n] = val;
        } else {
          int b = m >> 11, s = m & 2047, h = n >> 7, hd = n & 127;
          Db[(((size_t)(b * 16 + h)) * 2048 + s) * 128 + hd] = f2bf(val);
        }
      }
    }
  }
}

// ---------------- Flash attention: q,k (B,H,S,HD), vt (B,H,HD,S), o (B,S,D) bf16 ----------------
// q pre-scaled by (1/sqrt(HD))*log2(e) so softmax uses exp2.
// 8 waves x 16 q-rows = 128-row q-block. Paired {xt, 15-xt} -> uniform 34 kv-tiles/block.
// Grid 256 blocks = 1/CU, all resident. bh = fid&31 keeps a head's blocks on one XCD.
// Direct staging (load->LDS immediately, nothing live across compute -> no spill).
__global__ __launch_bounds__(512) void attn_fwd(
    const u16* __restrict__ q, const u16* __restrict__ k, const u16* __restrict__ vt,
    u16* __restrict__ o) {
  const int fid = (int)blockIdx.x + 8 * (int)blockIdx.y;  // grid (8,32)
  const int bh = fid & 31, xt = fid >> 5;                 // 4 heads per XCD
  const u16* qh = q + (size_t)bh * S_ * HD_;
  const u16* kh = k + (size_t)bh * S_ * HD_;
  const u16* vth = vt + (size_t)bh * S_ * HD_;
  const int t = threadIdx.x, l = t & 63, w = t >> 6;
  __shared__ u16 Kl[64][136] __attribute__((aligned(16)));   // +8 pad
  __shared__ u16 Vl[128][72] __attribute__((aligned(16)));   // [hd][kv], +8 pad
  __shared__ u16 Pl[8][16][72] __attribute__((aligned(16))); // per-wave P
  const int b = bh >> 4, h = bh & 15;
  // staging geometry: K pass f=it*512+t: row=f>>4, col=(f&15)*8 (2 passes)
  //                   V pass f=it*512+t: row=f>>3, col=(f&7)*8  (2 passes)
  const int krr = t >> 4, krc = (t & 15) * 8;   // within-pass base (pass adds 32 rows)
  const int vrr = t >> 3, vrc = (t & 7) * 8;    // pass adds 64 rows

  for (int half = 0; half < 2; ++half) {
    const int qb = half ? (15 - xt) : xt;
    const int q0 = qb * 128;
    const int wrow0 = q0 + w * 16;              // wave's first q row
    const int qrow = wrow0 + (l & 15);
    bf16x8 qf[4];
#pragma unroll
    for (int kk = 0; kk < 4; ++kk)
      qf[kk] = *(const bf16x8*)&qh[(size_t)qrow * HD_ + kk * 32 + (l >> 4) * 8];
    f32x4 oacc[8];
#pragma unroll
    for (int i = 0; i < 8; ++i) oacc[i] = (f32x4){0.f, 0.f, 0.f, 0.f};
    float mrow[4] = {-1e30f, -1e30f, -1e30f, -1e30f};
    float lrow[4] = {0.f, 0.f, 0.f, 0.f};       // per-lane partial denominators

    const int ntile = 2 * qb + 2;
    for (int tk = 0; tk < ntile; ++tk) {
      const int kv0 = tk * 64;
      __syncthreads();                 // previous compute done: LDS writable
#pragma unroll
      for (int it = 0; it < 2; ++it) {
        int row = it * 32 + krr;
        *(uint4*)&Kl[row][krc] = *(const uint4*)&kh[(size_t)(kv0 + row) * HD_ + krc];
      }
#pragma unroll
      for (int it = 0; it < 2; ++it) {
        int row = it * 64 + vrr;
        *(uint4*)&Vl[row][vrc] = *(const uint4*)&vth[(size_t)row * S_ + kv0 + vrc];
      }
      __syncthreads();                 // LDS tile ready

      if (kv0 > wrow0 + 15) continue;  // fully masked for this wave (state untouched)

      f32x4 sf[4];
#pragma unroll
      for (int cb = 0; cb < 4; ++cb) sf[cb] = (f32x4){0.f, 0.f, 0.f, 0.f};
      __builtin_amdgcn_s_setprio(1);
#pragma unroll
      for (int kk = 0; kk < 4; ++kk) {
        const int ko = kk * 32 + (l >> 4) * 8;
#pragma unroll
        for (int cb = 0; cb < 4; ++cb) {
          bf16x8 bfr = *(const bf16x8*)&Kl[cb * 16 + (l & 15)][ko];
          sf[cb] = __builtin_amdgcn_mfma_f32_16x16x32_bf16(qf[kk], bfr, sf[cb], 0, 0, 0);
        }
      }
      __builtin_amdgcn_s_setprio(0);
      if (kv0 + 63 > wrow0) {  // diagonal tile for this wave: elementwise causal mask
#pragma unroll
        for (int cb = 0; cb < 4; ++cb) {
          int c_abs = kv0 + cb * 16 + (l & 15);
#pragma unroll
          for (int r = 0; r < 4; ++r)
            if (c_abs > wrow0 + (l >> 4) * 4 + r) sf[cb][r] = -1e30f;
        }
      }
      float fr[4], ps[4];
#pragma unroll
      for (int r = 0; r < 4; ++r) {
        float v0 = fmaxf(fmaxf(sf[0][r], sf[1][r]), fmaxf(sf[2][r], sf[3][r]));
        v0 = fmaxf(v0, __shfl_xor(v0, 1));
        v0 = fmaxf(v0, __shfl_xor(v0, 2));
        v0 = fmaxf(v0, __shfl_xor(v0, 4));
        v0 = fmaxf(v0, __shfl_xor(v0, 8));
        float Mn = fmaxf(mrow[r], v0);
        fr[r] = exp2f(mrow[r] - Mn);
        mrow[r] = Mn;
        ps[r] = 0.f;
      }
#pragma unroll
      for (int cb = 0; cb < 4; ++cb) {
#pragma unroll
        for (int r = 0; r < 4; ++r) {
          float p = exp2f(sf[cb][r] - mrow[r]);
          ps[r] += p;
          Pl[w][(l >> 4) * 4 + r][cb * 16 + (l & 15)] = f2bf(p);
        }
      }
#pragma unroll
      for (int r = 0; r < 4; ++r) lrow[r] = lrow[r] * fr[r] + ps[r];  // per-lane partial
#pragma unroll
      for (int i = 0; i < 8; ++i)
#pragma unroll
        for (int r = 0; r < 4; ++r) oacc[i][r] *= fr[r];
      __builtin_amdgcn_s_setprio(1);
#pragma unroll
      for (int ks = 0; ks < 2; ++ks) {
        bf16x8 pa = *(const bf16x8*)&Pl[w][l & 15][ks * 32 + (l >> 4) * 8];
#pragma unroll
        for (int nf = 0; nf < 8; ++nf) {
          bf16x8 vb = *(const bf16x8*)&Vl[nf * 16 + (l & 15)][ks * 32 + (l >> 4) * 8];
          oacc[nf] = __builtin_amdgcn_mfma_f32_16x16x32_bf16(pa, vb, oacc[nf], 0, 0, 0);
        }
      }
      __builtin_amdgcn_s_setprio(0);
    }

    float inv[4];
#pragma unroll
    for (int r = 0; r < 4; ++r) {     // reduce deferred per-lane partials
      float s = lrow[r];
      s += __shfl_xor(s, 1);
      s += __shfl_xor(s, 2);
      s += __shfl_xor(s, 4);
      s += __shfl_xor(s, 8);
      inv[r] = 1.f / s;
    }
#pragma unroll
    for (int nf = 0; nf < 8; ++nf) {
#pragma unroll
      for (int r = 0; r < 4; ++r) {
        int row = wrow0 + (l >> 4) * 4 + r;
        int col = h * 128 + nf * 16 + (l & 15);
        o[((size_t)(b * 2048 + row)) * 2048 + col] = f2bf(oacc[nf][r] * inv[r]);
      }
    }
  }
}

extern "C" void kernel_launch(void* const* d_in, const int* in_sizes, int n_in,
                              void* d_out, int out_size, void* d_ws, size_t ws_size,
                              hipStream_t stream) {
  (void)in_sizes; (void)n_in; (void)out_size; (void)ws_size;
  const float* hs   = (const float*)d_in[0];
  const float* fcos = (const float*)d_in[1];
  const float* fsin = (const float*)d_in[2];
  // d_in[3] = attention_mask: causal, implemented directly.
  const float* wq = (const float*)d_in[4];
  const float* wk = (const float*)d_in[5];
  const float* wv = (const float*)d_in[6];
  const float* wo = (const float*)d_in[7];
  float* out = (float*)d_out;
  char* ws = (char*)d_ws;
  // ws layout (bytes), total 128 MiB
  u16* hsb = (u16*)(ws + 0);          // 16 MiB  hs bf16 (B,S,D)
  u16* wqb = (u16*)(ws + 16777216);
  u16* wkb = (u16*)(ws + 25165824);
  u16* wvb = (u16*)(ws + 33554432);
  u16* wob = (u16*)(ws + 41943040);
  u16* qb  = (u16*)(ws + 50331648);   // (B,H,S,HD) bf16
  u16* kb  = (u16*)(ws + 67108864);
  u16* vb  = (u16*)(ws + 83886080);
  u16* vtb = (u16*)(ws + 100663296);  // (B,H,HD,S) bf16
  u16* aob = (u16*)(ws + 117440512);  // (B,S,D) bf16 attention output

  cvt_bf16<<<8192, 256, 0, stream>>>(hs, hsb, 2097152);
  cvt_bf16<<<4096, 256, 0, stream>>>(wq, wqb, 1048576);
  cvt_bf16<<<4096, 256, 0, stream>>>(wk, wkb, 1048576);
  cvt_bf16<<<4096, 256, 0, stream>>>(wv, wvb, 1048576);
  cvt_bf16<<<4096, 256, 0, stream>>>(wo, wob, 1048576);

  gemm_bt<<<dim3(16, 32, 3), 256, 0, stream>>>(hsb, wqb, wkb, wvb, qb, kb, vb, nullptr, 0);

  const float qscale = (float)(0.08838834764831845 * 1.4426950408889634); // 1/sqrt(128)*log2(e)
  rope_k<<<4096, 256, 0, stream>>>(qb, fcos, fsin, qscale);
  rope_k<<<4096, 256, 0, stream>>>(kb, fcos, fsin, 1.0f);

  transpose_v<<<dim3(32, 2, 32), 256, 0, stream>>>(vb, vtb);

  attn_fwd<<<dim3(8, 32), 512, 0, stream>>>(qb, kb, vtb, aob);

  gemm_bt<<<dim3(16, 32, 1), 256, 0, stream>>>(aob, wob, wob, wob,
                                               nullptr, nullptr, nullptr, out, 1);
}

// Round 8
// 463.656 us; speedup vs baseline: 1.2167x; 1.0073x over previous
//
#include <hip/hip_runtime.h>

typedef unsigned short u16;
typedef unsigned int u32;
typedef __bf16 bf16x8 __attribute__((ext_vector_type(8)));
typedef float f32x4 __attribute__((ext_vector_type(4)));

#define B_ 2
#define S_ 2048
#define D_ 2048
#define H_ 16
#define HD_ 128

__device__ __forceinline__ u16 f2bf(float f) {
  u32 u = __float_as_uint(f);
  u32 r = (u + 0x7fffu + ((u >> 16) & 1u)) >> 16;
  return (u16)r;
}
__device__ __forceinline__ float bf2f(u16 b) {
  return __uint_as_float(((u32)b) << 16);
}

// async global->LDS, 16B per lane. LDS dest must be linear in lane order.
__device__ __forceinline__ void gll16(const void* g, void* lds) {
  __builtin_amdgcn_global_load_lds(
      (const __attribute__((address_space(1))) u32*)g,
      (__attribute__((address_space(3))) u32*)lds, 16, 0, 0);
}

// ---------------- f32 -> bf16 cast ----------------
__global__ __launch_bounds__(256) void cvt_bf16(const float* __restrict__ in,
                                                u16* __restrict__ out, int n4) {
  int i = blockIdx.x * 256 + threadIdx.x;
  if (i >= n4) return;
  float4 v = ((const float4*)in)[i];
  u16 o[4] __attribute__((aligned(8)));
  o[0] = f2bf(v.x); o[1] = f2bf(v.y); o[2] = f2bf(v.z); o[3] = f2bf(v.w);
  ((ushort4*)out)[i] = *(const ushort4*)o;
}

// ---------------- RoPE (in-place on (B,H,S,HD) bf16), optional scale ----------------
__global__ __launch_bounds__(256) void rope_k(u16* __restrict__ x,
                                              const float* __restrict__ cosb,
                                              const float* __restrict__ sinb,
                                              float scale) {
  int tid = blockIdx.x * 256 + threadIdx.x;  // 8 elems per thread
  int flat = tid << 3;
  int hd0 = flat & (HD_ - 1);
  int s = (flat >> 7) & (S_ - 1);
  u16 e[8] __attribute__((aligned(16)));
  *(uint4*)e = *(const uint4*)&x[flat];
  const float* cp = cosb + s * (HD_ / 2) + (hd0 >> 1);
  const float* sp = sinb + s * (HD_ / 2) + (hd0 >> 1);
#pragma unroll
  for (int i = 0; i < 4; ++i) {
    float xr = bf2f(e[2 * i]), xi = bf2f(e[2 * i + 1]);
    float c = cp[i], sn = sp[i];
    e[2 * i]     = f2bf((xr * c - xi * sn) * scale);
    e[2 * i + 1] = f2bf((xr * sn + xi * c) * scale);
  }
  *(uint4*)&x[flat] = *(const uint4*)e;
}

// ---------------- V transpose: (B,H,S,HD) -> (B,H,HD,S) ----------------
__global__ __launch_bounds__(256) void transpose_v(const u16* __restrict__ v,
                                                   u16* __restrict__ vt) {
  __shared__ u16 tile[64][72];
  int s0 = blockIdx.x * 64, hd0 = blockIdx.y * 64, bh = blockIdx.z;
  const u16* vh = v + (size_t)bh * S_ * HD_;
  u16* vth = vt + (size_t)bh * S_ * HD_;
  int t = threadIdx.x;
#pragma unroll
  for (int it = 0; it < 2; ++it) {
    int f = it * 256 + t;
    int r = f >> 3, c = (f & 7) * 8;
    *(uint4*)&tile[r][c] = *(const uint4*)&vh[(size_t)(s0 + r) * HD_ + hd0 + c];
  }
  __syncthreads();
#pragma unroll
  for (int it = 0; it < 2; ++it) {
    int f = it * 256 + t;
    int r = f >> 3, c = (f & 7) * 8;   // r: hd row of vt, c: s col chunk
    u16 tmp[8] __attribute__((aligned(16)));
#pragma unroll
    for (int j = 0; j < 8; ++j) tmp[j] = tile[c + j][r];
    *(uint4*)&vth[(size_t)(hd0 + r) * S_ + s0 + c] = *(const uint4*)tmp;
  }
}

// ---------------- 256x256 8-phase GEMM  C[m,n] = sum_k A[m,k]*W[n,k] ----------------
// MODE 0: A=(4096x2048) hs, W = [Wq|Wk|Wv] (N=6144), out bf16 permuted (B,H,S,HD). grid 384.
// MODE 1: A=(4096x2048) attn-out, W = Wo (N=2048), out f32 (B,S,D). grid 128.
// 8 waves (2M x 4N), BK=64, 128KB LDS dbuf. T2 swizzle: LDS[row][byte c] holds
// global byte c ^ ((row&7)<<4); gll16 keeps linear LDS dest, source pre-swizzled.
// Per K-tile: 4 phases {12 ds_read | stage | bar | lgkm0 | 16 MFMA | bar}, vmcnt(0) at tile end only.
#define SBAR()  { __builtin_amdgcn_sched_barrier(0); __builtin_amdgcn_s_barrier(); }
#define LGKM0() { asm volatile("s_waitcnt lgkmcnt(0)" ::: "memory"); __builtin_amdgcn_sched_barrier(0); }
#define VM0()   { asm volatile("s_waitcnt vmcnt(0)" ::: "memory"); __builtin_amdgcn_sched_barrier(0); }

#define LOADQ(mh, nh, bi)                                                      \
  {                                                                            \
    const char* Ab = (const char*)(ldsA + (bi)*32768);                         \
    const char* Bb = (const char*)(ldsB + (bi)*32768);                         \
    _Pragma("unroll")                                                          \
    for (int i = 0; i < 4; ++i) {                                              \
      int row = wm * 128 + (mh)*64 + i * 16 + (l & 15);                        \
      a_[i][0] = *(const bf16x8*)(Ab + row * 128 + ab0);                       \
      a_[i][1] = *(const bf16x8*)(Ab + row * 128 + (ab0 ^ 64));                \
    }                                                                          \
    _Pragma("unroll")                                                          \
    for (int j = 0; j < 2; ++j) {                                              \
      int row = wn * 64 + (nh)*32 + j * 16 + (l & 15);                         \
      b_[j][0] = *(const bf16x8*)(Bb + row * 128 + ab0);                       \
      b_[j][1] = *(const bf16x8*)(Bb + row * 128 + (ab0 ^ 64));                \
    }                                                                          \
  }

#define MFMAQ(mh, nh)                                                          \
  _Pragma("unroll")                                                            \
  for (int i = 0; i < 4; ++i)                                                  \
    _Pragma("unroll")                                                          \
    for (int j = 0; j < 2; ++j)                                                \
      _Pragma("unroll")                                                        \
      for (int kk = 0; kk < 2; ++kk)                                           \
        acc[(mh)*4 + i][(nh)*2 + j] = __builtin_amdgcn_mfma_f32_16x16x32_bf16( \
            a_[i][kk], b_[j][kk], acc[(mh)*4 + i][(nh)*2 + j], 0, 0, 0);

#define PHASE(mh, nh, bi, STAGE, TAIL)                                         \
  {                                                                            \
    bf16x8 a_[4][2], b_[2][2];                                                 \
    LOADQ(mh, nh, bi)                                                          \
    STAGE                                                                      \
    SBAR()                                                                     \
    LGKM0()                                                                    \
    __builtin_amdgcn_s_setprio(1);                                             \
    MFMAQ(mh, nh)                                                              \
    __builtin_amdgcn_s_setprio(0);                                             \
    TAIL                                                                       \
    SBAR()                                                                     \
  }

template <int MODE>
__global__ __launch_bounds__(512, 2) void gemm256(
    const u16* __restrict__ A,
    const u16* __restrict__ W0, const u16* __restrict__ W1, const u16* __restrict__ W2,
    u16* __restrict__ Dq, u16* __restrict__ Dk, u16* __restrict__ Dv,
    float* __restrict__ DF) {
  extern __shared__ __align__(16) u16 lds[];
  u16* ldsA = lds;            // [bi][256][64] at bi*32768
  u16* ldsB = lds + 16384;
  const int bx = (int)blockIdx.x;
  const int nwg = (MODE == 0) ? 384 : 128;
  const int cpx = nwg >> 3;
  const int wg = (bx & 7) * cpx + (bx >> 3);   // bijective XCD swizzle (nwg % 8 == 0)
  const int mt = wg & 15, nt = wg >> 4;
  const int m0 = mt * 256;
  const u16* W;
  int n0w, wsel = 0;
  if (MODE == 0) {
    wsel = nt >> 3;
    W = (wsel == 0) ? W0 : ((wsel == 1) ? W1 : W2);
    n0w = (nt & 7) * 256;
  } else {
    W = W0;
    n0w = nt * 256;
  }
  const int t = threadIdx.x, l = t & 63;
  const int w = t >> 6, wm = w >> 2, wn = w & 3;
  // staging: sweep s covers rows [s*64, s*64+64); thread t -> row s*64 + (t>>3), byte col (t&7)*16
  const int srow = t >> 3;
  const int scol = (((t & 7) * 16) ^ ((srow & 7) << 4)) >> 1;  // pre-swizzled source elem col
  const u16* pAs = A + (size_t)(m0 + srow) * 2048 + scol;
  const u16* pBs = W + (size_t)(n0w + srow) * 2048 + scol;
  const int ab0 = ((l >> 4) * 16) ^ ((l & 7) << 4);  // kk=0 frag byte col (swizzled)

  f32x4 acc[8][4];
#pragma unroll
  for (int i = 0; i < 8; ++i)
#pragma unroll
    for (int j = 0; j < 4; ++j) acc[i][j] = (f32x4){0.f, 0.f, 0.f, 0.f};

  // prologue: tile 0 -> buf 0
#pragma unroll
  for (int s = 0; s < 4; ++s) {
    gll16(pAs + s * 131072, ldsA + s * 4096 + t * 8);
    gll16(pBs + s * 131072, ldsB + s * 4096 + t * 8);
  }
  VM0()
  SBAR()

#pragma unroll 2
  for (int tt = 0; tt < 32; ++tt) {
    const int bi = tt & 1;
    const int dst = (bi ^ 1) * 32768;
    const int ko = (tt + 1) << 6;
    const bool pf = (tt < 31);
    PHASE(0, 0, bi,
      { if (pf) {
          gll16(pAs + ko,           ldsA + dst + t * 8);
          gll16(pAs + ko + 131072,  ldsA + dst + 4096 + t * 8);
          gll16(pBs + ko,           ldsB + dst + t * 8);
          gll16(pBs + ko + 131072,  ldsB + dst + 4096 + t * 8);
      } }, {})
    PHASE(0, 1, bi,
      { if (pf) {
          gll16(pAs + ko + 262144,  ldsA + dst + 8192 + t * 8);
          gll16(pAs + ko + 393216,  ldsA + dst + 12288 + t * 8);
          gll16(pBs + ko + 262144,  ldsB + dst + 8192 + t * 8);
          gll16(pBs + ko + 393216,  ldsB + dst + 12288 + t * 8);
      } }, {})
    PHASE(1, 0, bi, {}, {})
    PHASE(1, 1, bi, {}, { asm volatile("s_waitcnt vmcnt(0)" ::: "memory"); })
  }

  // epilogue
  if (MODE == 0) {
    u16* Db = (wsel == 0) ? Dq : ((wsel == 1) ? Dk : Dv);
#pragma unroll
    for (int fi = 0; fi < 8; ++fi) {
#pragma unroll
      for (int fj = 0; fj < 4; ++fj) {
#pragma unroll
        for (int r = 0; r < 4; ++r) {
          int m = m0 + wm * 128 + fi * 16 + (l >> 4) * 4 + r;
          int nn = n0w + wn * 64 + fj * 16 + (l & 15);
          int b = m >> 11, s = m & 2047, h = nn >> 7, hd = nn & 127;
          Db[(((size_t)(b * 16 + h)) * 2048 + s) * 128 + hd] = f2bf(acc[fi][fj][r]);
        }
      }
    }
  } else {
#pragma unroll
    for (int fi = 0; fi < 8; ++fi) {
#pragma unroll
      for (int fj = 0; fj < 4; ++fj) {
#pragma unroll
        for (int r = 0; r < 4; ++r) {
          int m = m0 + wm * 128 + fi * 16 + (l >> 4) * 4 + r;
          int nn = n0w + wn * 64 + fj * 16 + (l & 15);
          DF[(size_t)m * 2048 + nn] = acc[fi][fj][r];
        }
      }
    }
  }
}

// ---------------- Flash attention: q,k (B,H,S,HD), vt (B,H,HD,S), o (B,S,D) bf16 ----------------
// (unchanged from round 2 revision)
__global__ __launch_bounds__(512) void attn_fwd(
    const u16* __restrict__ q, const u16* __restrict__ k, const u16* __restrict__ vt,
    u16* __restrict__ o) {
  const int fid = (int)blockIdx.x + 8 * (int)blockIdx.y;  // grid (8,32)
  const int bh = fid & 31, xt = fid >> 5;                 // 4 heads per XCD
  const u16* qh = q + (size_t)bh * S_ * HD_;
  const u16* kh = k + (size_t)bh * S_ * HD_;
  const u16* vth = vt + (size_t)bh * S_ * HD_;
  const int t = threadIdx.x, l = t & 63, w = t >> 6;
  __shared__ u16 Kl[64][136] __attribute__((aligned(16)));
  __shared__ u16 Vl[128][72] __attribute__((aligned(16)));
  __shared__ u16 Pl[8][16][72] __attribute__((aligned(16)));
  const int b = bh >> 4, h = bh & 15;
  const int krr = t >> 4, krc = (t & 15) * 8;
  const int vrr = t >> 3, vrc = (t & 7) * 8;

  for (int half = 0; half < 2; ++half) {
    const int qb = half ? (15 - xt) : xt;
    const int q0 = qb * 128;
    const int wrow0 = q0 + w * 16;
    const int qrow = wrow0 + (l & 15);
    bf16x8 qf[4];
#pragma unroll
    for (int kk = 0; kk < 4; ++kk)
      qf[kk] = *(const bf16x8*)&qh[(size_t)qrow * HD_ + kk * 32 + (l >> 4) * 8];
    f32x4 oacc[8];
#pragma unroll
    for (int i = 0; i < 8; ++i) oacc[i] = (f32x4){0.f, 0.f, 0.f, 0.f};
    float mrow[4] = {-1e30f, -1e30f, -1e30f, -1e30f};
    float lrow[4] = {0.f, 0.f, 0.f, 0.f};

    const int ntile = 2 * qb + 2;
    for (int tk = 0; tk < ntile; ++tk) {
      const int kv0 = tk * 64;
      __syncthreads();
#pragma unroll
      for (int it = 0; it < 2; ++it) {
        int row = it * 32 + krr;
        *(uint4*)&Kl[row][krc] = *(const uint4*)&kh[(size_t)(kv0 + row) * HD_ + krc];
      }
#pragma unroll
      for (int it = 0; it < 2; ++it) {
        int row = it * 64 + vrr;
        *(uint4*)&Vl[row][vrc] = *(const uint4*)&vth[(size_t)row * S_ + kv0 + vrc];
      }
      __syncthreads();

      if (kv0 > wrow0 + 15) continue;

      f32x4 sf[4];
#pragma unroll
      for (int cb = 0; cb < 4; ++cb) sf[cb] = (f32x4){0.f, 0.f, 0.f, 0.f};
      __builtin_amdgcn_s_setprio(1);
#pragma unroll
      for (int kk = 0; kk < 4; ++kk) {
        const int ko = kk * 32 + (l >> 4) * 8;
#pragma unroll
        for (int cb = 0; cb < 4; ++cb) {
          bf16x8 bfr = *(const bf16x8*)&Kl[cb * 16 + (l & 15)][ko];
          sf[cb] = __builtin_amdgcn_mfma_f32_16x16x32_bf16(qf[kk], bfr, sf[cb], 0, 0, 0);
        }
      }
      __builtin_amdgcn_s_setprio(0);
      if (kv0 + 63 > wrow0) {
#pragma unroll
        for (int cb = 0; cb < 4; ++cb) {
          int c_abs = kv0 + cb * 16 + (l & 15);
#pragma unroll
          for (int r = 0; r < 4; ++r)
            if (c_abs > wrow0 + (l >> 4) * 4 + r) sf[cb][r] = -1e30f;
        }
      }
      float fr[4], ps[4];
#pragma unroll
      for (int r = 0; r < 4; ++r) {
        float v0 = fmaxf(fmaxf(sf[0][r], sf[1][r]), fmaxf(sf[2][r], sf[3][r]));
        v0 = fmaxf(v0, __shfl_xor(v0, 1));
        v0 = fmaxf(v0, __shfl_xor(v0, 2));
        v0 = fmaxf(v0, __shfl_xor(v0, 4));
        v0 = fmaxf(v0, __shfl_xor(v0, 8));
        float Mn = fmaxf(mrow[r], v0);
        fr[r] = exp2f(mrow[r] - Mn);
        mrow[r] = Mn;
        ps[r] = 0.f;
      }
#pragma unroll
      for (int cb = 0; cb < 4; ++cb) {
#pragma unroll
        for (int r = 0; r < 4; ++r) {
          float p = exp2f(sf[cb][r] - mrow[r]);
          ps[r] += p;
          Pl[w][(l >> 4) * 4 + r][cb * 16 + (l & 15)] = f2bf(p);
        }
      }
#pragma unroll
      for (int r = 0; r < 4; ++r) lrow[r] = lrow[r] * fr[r] + ps[r];
#pragma unroll
      for (int i = 0; i < 8; ++i)
#pragma unroll
        for (int r = 0; r < 4; ++r) oacc[i][r] *= fr[r];
      __builtin_amdgcn_s_setprio(1);
#pragma unroll
      for (int ks = 0; ks < 2; ++ks) {
        bf16x8 pa = *(const bf16x8*)&Pl[w][l & 15][ks * 32 + (l >> 4) * 8];
#pragma unroll
        for (int nf = 0; nf < 8; ++nf) {
          bf16x8 vb = *(const bf16x8*)&Vl[nf * 16 + (l & 15)][ks * 32 + (l >> 4) * 8];
          oacc[nf] = __builtin_amdgcn_mfma_f32_16x16x32_bf16(pa, vb, oacc[nf], 0, 0, 0);
        }
      }
      __builtin_amdgcn_s_setprio(0);
    }

    float inv[4];
#pragma unroll
    for (int r = 0; r < 4; ++r) {
      float s = lrow[r];
      s += __shfl_xor(s, 1);
      s += __shfl_xor(s, 2);
      s += __shfl_xor(s, 4);
      s += __shfl_xor(s, 8);
      inv[r] = 1.f / s;
    }
#pragma unroll
    for (int nf = 0; nf < 8; ++nf) {
#pragma unroll
      for (int r = 0; r < 4; ++r) {
        int row = wrow0 + (l >> 4) * 4 + r;
        int col = h * 128 + nf * 16 + (l & 15);
        o[((size_t)(b * 2048 + row)) * 2048 + col] = f2bf(oacc[nf][r] * inv[r]);
      }
    }
  }
}

extern "C" void kernel_launch(void* const* d_in, const int* in_sizes, int n_in,
                              void* d_out, int out_size, void* d_ws, size_t ws_size,
                              hipStream_t stream) {
  (void)in_sizes; (void)n_in; (void)out_size; (void)ws_size;
  const float* hs   = (const float*)d_in[0];
  const float* fcos = (const float*)d_in[1];
  const float* fsin = (const float*)d_in[2];
  // d_in[3] = attention_mask: causal, implemented directly.
  const float* wq = (const float*)d_in[4];
  const float* wk = (const float*)d_in[5];
  const float* wv = (const float*)d_in[6];
  const float* wo = (const float*)d_in[7];
  float* out = (float*)d_out;
  char* ws = (char*)d_ws;
  u16* hsb = (u16*)(ws + 0);          // 16 MiB  hs bf16 (B,S,D)
  u16* wqb = (u16*)(ws + 16777216);
  u16* wkb = (u16*)(ws + 25165824);
  u16* wvb = (u16*)(ws + 33554432);
  u16* wob = (u16*)(ws + 41943040);
  u16* qb  = (u16*)(ws + 50331648);   // (B,H,S,HD) bf16
  u16* kb  = (u16*)(ws + 67108864);
  u16* vb  = (u16*)(ws + 83886080);
  u16* vtb = (u16*)(ws + 100663296);  // (B,H,HD,S) bf16
  u16* aob = (u16*)(ws + 117440512);  // (B,S,D) bf16 attention output

  // allow 128KB dynamic LDS (idempotent; host-side, graph-capture safe)
  hipFuncSetAttribute((const void*)gemm256<0>,
                      hipFuncAttributeMaxDynamicSharedMemorySize, 131072);
  hipFuncSetAttribute((const void*)gemm256<1>,
                      hipFuncAttributeMaxDynamicSharedMemorySize, 131072);

  cvt_bf16<<<8192, 256, 0, stream>>>(hs, hsb, 2097152);
  cvt_bf16<<<4096, 256, 0, stream>>>(wq, wqb, 1048576);
  cvt_bf16<<<4096, 256, 0, stream>>>(wk, wkb, 1048576);
  cvt_bf16<<<4096, 256, 0, stream>>>(wv, wvb, 1048576);
  cvt_bf16<<<4096, 256, 0, stream>>>(wo, wob, 1048576);

  gemm256<0><<<384, 512, 131072, stream>>>(hsb, wqb, wkb, wvb, qb, kb, vb, nullptr);

  const float qscale = (float)(0.08838834764831845 * 1.4426950408889634); // 1/sqrt(128)*log2(e)
  rope_k<<<4096, 256, 0, stream>>>(qb, fcos, fsin, qscale);
  rope_k<<<4096, 256, 0, stream>>>(kb, fcos, fsin, 1.0f);

  transpose_v<<<dim3(32, 2, 32), 256, 0, stream>>>(vb, vtb);

  attn_fwd<<<dim3(8, 32), 512, 0, stream>>>(qb, kb, vtb, aob);

  gemm256<1><<<128, 512, 131072, stream>>>(aob, wob, nullptr, nullptr,
                                           nullptr, nullptr, nullptr, out);
}

// Round 10
// 419.324 us; speedup vs baseline: 1.3454x; 1.1057x over previous
//
#include <hip/hip_runtime.h>

typedef unsigned short u16;
typedef unsigned int u32;
typedef __bf16 bf16x8 __attribute__((ext_vector_type(8)));
typedef float f32x4 __attribute__((ext_vector_type(4)));

#define B_ 2
#define S_ 2048
#define D_ 2048
#define H_ 16
#define HD_ 128

__device__ __forceinline__ u16 f2bf(float f) {
  u32 u = __float_as_uint(f);
  u32 r = (u + 0x7fffu + ((u >> 16) & 1u)) >> 16;
  return (u16)r;
}
__device__ __forceinline__ float bf2f(u16 b) {
  return __uint_as_float(((u32)b) << 16);
}

// async global->LDS, 16B per lane. LDS dest must be linear in lane order.
__device__ __forceinline__ void gll16(const void* g, void* lds) {
  __builtin_amdgcn_global_load_lds(
      (const __attribute__((address_space(1))) u32*)g,
      (__attribute__((address_space(3))) u32*)lds, 16, 0, 0);
}

// ---------------- f32 -> bf16 cast ----------------
__global__ __launch_bounds__(256) void cvt_bf16(const float* __restrict__ in,
                                                u16* __restrict__ out, int n4) {
  int i = blockIdx.x * 256 + threadIdx.x;
  if (i >= n4) return;
  float4 v = ((const float4*)in)[i];
  u16 o[4] __attribute__((aligned(8)));
  o[0] = f2bf(v.x); o[1] = f2bf(v.y); o[2] = f2bf(v.z); o[3] = f2bf(v.w);
  ((ushort4*)out)[i] = *(const ushort4*)o;
}

// ---------------- RoPE (in-place on (B,H,S,HD) bf16), optional scale ----------------
__global__ __launch_bounds__(256) void rope_k(u16* __restrict__ x,
                                              const float* __restrict__ cosb,
                                              const float* __restrict__ sinb,
                                              float scale) {
  int tid = blockIdx.x * 256 + threadIdx.x;  // 8 elems per thread
  int flat = tid << 3;
  int hd0 = flat & (HD_ - 1);
  int s = (flat >> 7) & (S_ - 1);
  u16 e[8] __attribute__((aligned(16)));
  *(uint4*)e = *(const uint4*)&x[flat];
  const float* cp = cosb + s * (HD_ / 2) + (hd0 >> 1);
  const float* sp = sinb + s * (HD_ / 2) + (hd0 >> 1);
#pragma unroll
  for (int i = 0; i < 4; ++i) {
    float xr = bf2f(e[2 * i]), xi = bf2f(e[2 * i + 1]);
    float c = cp[i], sn = sp[i];
    e[2 * i]     = f2bf((xr * c - xi * sn) * scale);
    e[2 * i + 1] = f2bf((xr * sn + xi * c) * scale);
  }
  *(uint4*)&x[flat] = *(const uint4*)e;
}

// ---------------- V transpose: (B,H,S,HD) -> (B,H,HD,S) ----------------
__global__ __launch_bounds__(256) void transpose_v(const u16* __restrict__ v,
                                                   u16* __restrict__ vt) {
  __shared__ u16 tile[64][72];
  int s0 = blockIdx.x * 64, hd0 = blockIdx.y * 64, bh = blockIdx.z;
  const u16* vh = v + (size_t)bh * S_ * HD_;
  u16* vth = vt + (size_t)bh * S_ * HD_;
  int t = threadIdx.x;
#pragma unroll
  for (int it = 0; it < 2; ++it) {
    int f = it * 256 + t;
    int r = f >> 3, c = (f & 7) * 8;
    *(uint4*)&tile[r][c] = *(const uint4*)&vh[(size_t)(s0 + r) * HD_ + hd0 + c];
  }
  __syncthreads();
#pragma unroll
  for (int it = 0; it < 2; ++it) {
    int f = it * 256 + t;
    int r = f >> 3, c = (f & 7) * 8;   // r: hd row of vt, c: s col chunk
    u16 tmp[8] __attribute__((aligned(16)));
#pragma unroll
    for (int j = 0; j < 8; ++j) tmp[j] = tile[c + j][r];
    *(uint4*)&vth[(size_t)(hd0 + r) * S_ + s0 + c] = *(const uint4*)tmp;
  }
}

// ---------------- 128x256 triple-buffered GEMM  C[m,n] = sum_k A[m,k]*W[n,k] ----------------
// MODE 0: A=(4096x2048) hs, W=[Wq|Wk|Wv] (N=6144), bf16 out permuted (B,H,S,HD). grid 768 = 3 rounds.
// MODE 1: A=(4096x2048) attn-out, W=Wo (N=2048), f32 out (B,S,D). grid 256 = 1 round.
// 8 waves (2M x 4N), per-wave 64x64 out. BK=64, LDS 3 x (16KB A + 32KB B) = 144KB.
// T4: prefetch distance 2 tiles, end-of-tile s_waitcnt vmcnt(6) (counted, never 0 in steady state).
// T2: XOR swizzle byte_col ^= (row&7)<<4; gll16 linear dest + pre-swizzled global source.
// Per tile: 2 phases {8 ds_read | (phase A: 6 gll16 prefetch) | bar | lgkm0 | 16 MFMA | bar}.
#define SBAR()  { __builtin_amdgcn_sched_barrier(0); __builtin_amdgcn_s_barrier(); }
#define LGKM0() { asm volatile("s_waitcnt lgkmcnt(0)" ::: "memory"); __builtin_amdgcn_sched_barrier(0); }
#define VMC6()  { asm volatile("s_waitcnt vmcnt(6)" ::: "memory"); __builtin_amdgcn_sched_barrier(0); }
#define VMC0()  { asm volatile("s_waitcnt vmcnt(0)" ::: "memory"); __builtin_amdgcn_sched_barrier(0); }

#define GPHASE(Ab, Bb, COL, PRE, TAILVM)                                        \
  {                                                                             \
    PRE                                                                         \
    bf16x8 a_[4], b_[4];                                                        \
    _Pragma("unroll") for (int i = 0; i < 4; ++i)                               \
      a_[i] = *(const bf16x8*)((Ab) + (wm * 64 + i * 16 + (l & 15)) * 128 + (COL)); \
    _Pragma("unroll") for (int j = 0; j < 4; ++j)                               \
      b_[j] = *(const bf16x8*)((Bb) + (wn * 64 + j * 16 + (l & 15)) * 128 + (COL)); \
    SBAR(); LGKM0();                                                            \
    __builtin_amdgcn_s_setprio(1);                                              \
    _Pragma("unroll") for (int i = 0; i < 4; ++i)                               \
      _Pragma("unroll") for (int j = 0; j < 4; ++j)                             \
        acc[i][j] = __builtin_amdgcn_mfma_f32_16x16x32_bf16(a_[i], b_[j], acc[i][j], 0, 0, 0); \
    __builtin_amdgcn_s_setprio(0);                                              \
    TAILVM                                                                      \
    SBAR();                                                                     \
  }

#define GTILE(cur, kpf, PF, TAILVM)                                             \
  {                                                                             \
    char* Ab = lds + (cur) * 49152;                                             \
    char* Bb = Ab + 16384;                                                      \
    GPHASE(Ab, Bb, ab0,                                                         \
      { if (PF) {                                                               \
          char* An = lds + (((cur) + 2) % 3) * 49152;                           \
          char* Bn = An + 16384;                                                \
          gll16(pAs + (kpf), An + t * 16);                                      \
          gll16(pAs + (kpf) + 131072, An + 8192 + t * 16);                      \
          gll16(pBs + (kpf), Bn + t * 16);                                      \
          gll16(pBs + (kpf) + 131072, Bn + 8192 + t * 16);                      \
          gll16(pBs + (kpf) + 262144, Bn + 16384 + t * 16);                     \
          gll16(pBs + (kpf) + 393216, Bn + 24576 + t * 16);                     \
      } }, {})                                                                  \
    GPHASE(Ab, Bb, ab1, {}, TAILVM)                                             \
  }

template <int MODE>
__global__ __launch_bounds__(512, 2) void gemm128(
    const u16* __restrict__ A,
    const u16* __restrict__ W0, const u16* __restrict__ W1, const u16* __restrict__ W2,
    u16* __restrict__ Dq, u16* __restrict__ Dk, u16* __restrict__ Dv,
    float* __restrict__ DF) {
  extern __shared__ __align__(16) char lds[];  // 3 x 49152
  const int bx = (int)blockIdx.x;
  const int nwg = (MODE == 0) ? 768 : 256;
  const int cpx = nwg >> 3;
  const int wg = (bx & 7) * cpx + (bx >> 3);   // bijective XCD swizzle (nwg % 8 == 0)
  const int mt = wg & 31, nt = wg >> 5;        // M-fast: nearby wg share B (weight) panel
  const int m0 = mt * 128;
  const u16* W;
  int n0w, wsel = 0;
  if (MODE == 0) {
    int ng = nt * 256;
    wsel = ng >> 11;
    W = (wsel == 0) ? W0 : ((wsel == 1) ? W1 : W2);
    n0w = ng & 2047;
  } else {
    W = W0;
    n0w = nt * 256;
  }
  const int t = threadIdx.x, l = t & 63;
  const int w = t >> 6, wm = w >> 2, wn = w & 3;
  // staging: thread t covers row (t>>3) within a 64-row sweep, byte col (t&7)*16 (pre-swizzled src)
  const int srow = t >> 3;
  const int scol = ((((t & 7) * 16) ^ ((srow & 7) << 4)) >> 1);  // elems
  const u16* pAs = A + (size_t)(m0 + srow) * 2048 + scol;
  const u16* pBs = W + (size_t)(n0w + srow) * 2048 + scol;
  const int ab0 = ((l >> 4) * 16) ^ ((l & 7) << 4);  // kstep0 frag byte col (swizzled)
  const int ab1 = ab0 ^ 64;                          // kstep1

  f32x4 acc[4][4];
#pragma unroll
  for (int i = 0; i < 4; ++i)
#pragma unroll
    for (int j = 0; j < 4; ++j) acc[i][j] = (f32x4){0.f, 0.f, 0.f, 0.f};

  // prologue: tile 0 -> buf0, tile 1 -> buf1 (6 loads each)
#pragma unroll
  for (int s = 0; s < 2; ++s) gll16(pAs + s * 131072, lds + s * 8192 + t * 16);
#pragma unroll
  for (int s = 0; s < 4; ++s) gll16(pBs + s * 131072, lds + 16384 + s * 8192 + t * 16);
#pragma unroll
  for (int s = 0; s < 2; ++s) gll16(pAs + 64 + s * 131072, lds + 49152 + s * 8192 + t * 16);
#pragma unroll
  for (int s = 0; s < 4; ++s) gll16(pBs + 64 + s * 131072, lds + 49152 + 16384 + s * 8192 + t * 16);
  VMC6()   // wait tile 0's 6 loads; tile 1's 6 stay in flight
  SBAR()

  for (int tb = 0; tb < 10; ++tb) {   // tiles 0..29, prefetch tiles 2..31
    GTILE(0, (tb * 3 + 2) * 64, 1, VMC6())
    GTILE(1, (tb * 3 + 3) * 64, 1, VMC6())
    GTILE(2, (tb * 3 + 4) * 64, 1, VMC6())
  }
  GTILE(0, 0, 0, VMC0())              // tile 30
  GTILE(1, 0, 0, {})                  // tile 31 (nothing outstanding)

  // epilogue
  if (MODE == 0) {
    u16* Db = (wsel == 0) ? Dq : ((wsel == 1) ? Dk : Dv);
#pragma unroll
    for (int fi = 0; fi < 4; ++fi) {
#pragma unroll
      for (int fj = 0; fj < 4; ++fj) {
#pragma unroll
        for (int r = 0; r < 4; ++r) {
          int m = m0 + wm * 64 + fi * 16 + (l >> 4) * 4 + r;
          int nn = n0w + wn * 64 + fj * 16 + (l & 15);
          int b = m >> 11, s = m & 2047, h = nn >> 7, hd = nn & 127;
          Db[(((size_t)(b * 16 + h)) * 2048 + s) * 128 + hd] = f2bf(acc[fi][fj][r]);
        }
      }
    }
  } else {
#pragma unroll
    for (int fi = 0; fi < 4; ++fi) {
#pragma unroll
      for (int fj = 0; fj < 4; ++fj) {
#pragma unroll
        for (int r = 0; r < 4; ++r) {
          int m = m0 + wm * 64 + fi * 16 + (l >> 4) * 4 + r;
          int nn = n0w + wn * 64 + fj * 16 + (l & 15);
          DF[(size_t)m * 2048 + nn] = acc[fi][fj][r];
        }
      }
    }
  }
}

// ---------------- Flash attention: q,k (B,H,S,HD), vt (B,H,HD,S), o (B,S,D) bf16 ----------------
// (unchanged — passed round 8; no counters yet, so no blind edits)
__global__ __launch_bounds__(512) void attn_fwd(
    const u16* __restrict__ q, const u16* __restrict__ k, const u16* __restrict__ vt,
    u16* __restrict__ o) {
  const int fid = (int)blockIdx.x + 8 * (int)blockIdx.y;  // grid (8,32)
  const int bh = fid & 31, xt = fid >> 5;                 // 4 heads per XCD
  const u16* qh = q + (size_t)bh * S_ * HD_;
  const u16* kh = k + (size_t)bh * S_ * HD_;
  const u16* vth = vt + (size_t)bh * S_ * HD_;
  const int t = threadIdx.x, l = t & 63, w = t >> 6;
  __shared__ u16 Kl[64][136] __attribute__((aligned(16)));
  __shared__ u16 Vl[128][72] __attribute__((aligned(16)));
  __shared__ u16 Pl[8][16][72] __attribute__((aligned(16)));
  const int b = bh >> 4, h = bh & 15;
  const int krr = t >> 4, krc = (t & 15) * 8;
  const int vrr = t >> 3, vrc = (t & 7) * 8;

  for (int half = 0; half < 2; ++half) {
    const int qb = half ? (15 - xt) : xt;
    const int q0 = qb * 128;
    const int wrow0 = q0 + w * 16;
    const int qrow = wrow0 + (l & 15);
    bf16x8 qf[4];
#pragma unroll
    for (int kk = 0; kk < 4; ++kk)
      qf[kk] = *(const bf16x8*)&qh[(size_t)qrow * HD_ + kk * 32 + (l >> 4) * 8];
    f32x4 oacc[8];
#pragma unroll
    for (int i = 0; i < 8; ++i) oacc[i] = (f32x4){0.f, 0.f, 0.f, 0.f};
    float mrow[4] = {-1e30f, -1e30f, -1e30f, -1e30f};
    float lrow[4] = {0.f, 0.f, 0.f, 0.f};

    const int ntile = 2 * qb + 2;
    for (int tk = 0; tk < ntile; ++tk) {
      const int kv0 = tk * 64;
      __syncthreads();
#pragma unroll
      for (int it = 0; it < 2; ++it) {
        int row = it * 32 + krr;
        *(uint4*)&Kl[row][krc] = *(const uint4*)&kh[(size_t)(kv0 + row) * HD_ + krc];
      }
#pragma unroll
      for (int it = 0; it < 2; ++it) {
        int row = it * 64 + vrr;
        *(uint4*)&Vl[row][vrc] = *(const uint4*)&vth[(size_t)row * S_ + kv0 + vrc];
      }
      __syncthreads();

      if (kv0 > wrow0 + 15) continue;

      f32x4 sf[4];
#pragma unroll
      for (int cb = 0; cb < 4; ++cb) sf[cb] = (f32x4){0.f, 0.f, 0.f, 0.f};
      __builtin_amdgcn_s_setprio(1);
#pragma unroll
      for (int kk = 0; kk < 4; ++kk) {
        const int ko = kk * 32 + (l >> 4) * 8;
#pragma unroll
        for (int cb = 0; cb < 4; ++cb) {
          bf16x8 bfr = *(const bf16x8*)&Kl[cb * 16 + (l & 15)][ko];
          sf[cb] = __builtin_amdgcn_mfma_f32_16x16x32_bf16(qf[kk], bfr, sf[cb], 0, 0, 0);
        }
      }
      __builtin_amdgcn_s_setprio(0);
      if (kv0 + 63 > wrow0) {
#pragma unroll
        for (int cb = 0; cb < 4; ++cb) {
          int c_abs = kv0 + cb * 16 + (l & 15);
#pragma unroll
          for (int r = 0; r < 4; ++r)
            if (c_abs > wrow0 + (l >> 4) * 4 + r) sf[cb][r] = -1e30f;
        }
      }
      float fr[4], ps[4];
#pragma unroll
      for (int r = 0; r < 4; ++r) {
        float v0 = fmaxf(fmaxf(sf[0][r], sf[1][r]), fmaxf(sf[2][r], sf[3][r]));
        v0 = fmaxf(v0, __shfl_xor(v0, 1));
        v0 = fmaxf(v0, __shfl_xor(v0, 2));
        v0 = fmaxf(v0, __shfl_xor(v0, 4));
        v0 = fmaxf(v0, __shfl_xor(v0, 8));
        float Mn = fmaxf(mrow[r], v0);
        fr[r] = exp2f(mrow[r] - Mn);
        mrow[r] = Mn;
        ps[r] = 0.f;
      }
#pragma unroll
      for (int cb = 0; cb < 4; ++cb) {
#pragma unroll
        for (int r = 0; r < 4; ++r) {
          float p = exp2f(sf[cb][r] - mrow[r]);
          ps[r] += p;
          Pl[w][(l >> 4) * 4 + r][cb * 16 + (l & 15)] = f2bf(p);
        }
      }
#pragma unroll
      for (int r = 0; r < 4; ++r) lrow[r] = lrow[r] * fr[r] + ps[r];
#pragma unroll
      for (int i = 0; i < 8; ++i)
#pragma unroll
        for (int r = 0; r < 4; ++r) oacc[i][r] *= fr[r];
      __builtin_amdgcn_s_setprio(1);
#pragma unroll
      for (int ks = 0; ks < 2; ++ks) {
        bf16x8 pa = *(const bf16x8*)&Pl[w][l & 15][ks * 32 + (l >> 4) * 8];
#pragma unroll
        for (int nf = 0; nf < 8; ++nf) {
          bf16x8 vb = *(const bf16x8*)&Vl[nf * 16 + (l & 15)][ks * 32 + (l >> 4) * 8];
          oacc[nf] = __builtin_amdgcn_mfma_f32_16x16x32_bf16(pa, vb, oacc[nf], 0, 0, 0);
        }
      }
      __builtin_amdgcn_s_setprio(0);
    }

    float inv[4];
#pragma unroll
    for (int r = 0; r < 4; ++r) {
      float s = lrow[r];
      s += __shfl_xor(s, 1);
      s += __shfl_xor(s, 2);
      s += __shfl_xor(s, 4);
      s += __shfl_xor(s, 8);
      inv[r] = 1.f / s;
    }
#pragma unroll
    for (int nf = 0; nf < 8; ++nf) {
#pragma unroll
      for (int r = 0; r < 4; ++r) {
        int row = wrow0 + (l >> 4) * 4 + r;
        int col = h * 128 + nf * 16 + (l & 15);
        o[((size_t)(b * 2048 + row)) * 2048 + col] = f2bf(oacc[nf][r] * inv[r]);
      }
    }
  }
}

extern "C" void kernel_launch(void* const* d_in, const int* in_sizes, int n_in,
                              void* d_out, int out_size, void* d_ws, size_t ws_size,
                              hipStream_t stream) {
  (void)in_sizes; (void)n_in; (void)out_size; (void)ws_size;
  const float* hs   = (const float*)d_in[0];
  const float* fcos = (const float*)d_in[1];
  const float* fsin = (const float*)d_in[2];
  // d_in[3] = attention_mask: causal, implemented directly.
  const float* wq = (const float*)d_in[4];
  const float* wk = (const float*)d_in[5];
  const float* wv = (const float*)d_in[6];
  const float* wo = (const float*)d_in[7];
  float* out = (float*)d_out;
  char* ws = (char*)d_ws;
  u16* hsb = (u16*)(ws + 0);          // 16 MiB  hs bf16 (B,S,D)
  u16* wqb = (u16*)(ws + 16777216);
  u16* wkb = (u16*)(ws + 25165824);
  u16* wvb = (u16*)(ws + 33554432);
  u16* wob = (u16*)(ws + 41943040);
  u16* qb  = (u16*)(ws + 50331648);   // (B,H,S,HD) bf16
  u16* kb  = (u16*)(ws + 67108864);
  u16* vb  = (u16*)(ws + 83886080);
  u16* vtb = (u16*)(ws + 100663296);  // (B,H,HD,S) bf16
  u16* aob = (u16*)(ws + 117440512);  // (B,S,D) bf16 attention output

  // allow 144KB dynamic LDS (idempotent; host-side, graph-capture safe)
  hipFuncSetAttribute((const void*)gemm128<0>,
                      hipFuncAttributeMaxDynamicSharedMemorySize, 147456);
  hipFuncSetAttribute((const void*)gemm128<1>,
                      hipFuncAttributeMaxDynamicSharedMemorySize, 147456);

  cvt_bf16<<<8192, 256, 0, stream>>>(hs, hsb, 2097152);
  cvt_bf16<<<4096, 256, 0, stream>>>(wq, wqb, 1048576);
  cvt_bf16<<<4096, 256, 0, stream>>>(wk, wkb, 1048576);
  cvt_bf16<<<4096, 256, 0, stream>>>(wv, wvb, 1048576);
  cvt_bf16<<<4096, 256, 0, stream>>>(wo, wob, 1048576);

  gemm128<0><<<768, 512, 147456, stream>>>(hsb, wqb, wkb, wvb, qb, kb, vb, nullptr);

  const float qscale = (float)(0.08838834764831845 * 1.4426950408889634); // 1/sqrt(128)*log2(e)
  rope_k<<<4096, 256, 0, stream>>>(qb, fcos, fsin, qscale);
  rope_k<<<4096, 256, 0, stream>>>(kb, fcos, fsin, 1.0f);

  transpose_v<<<dim3(32, 2, 32), 256, 0, stream>>>(vb, vtb);

  attn_fwd<<<dim3(8, 32), 512, 0, stream>>>(qb, kb, vtb, aob);

  gemm128<1><<<256, 512, 147456, stream>>>(aob, wob, nullptr, nullptr,
                                           nullptr, nullptr, nullptr, out);
}